// Round 7
// baseline (176.500 us; speedup 1.0000x reference)
//
#include <hip/hip_runtime.h>

#define B_SZ 4096
#define N_IN 4096
#define N_CTX 512
#define UNITS 4096
#define RANK 256
#define ZSPLIT 16

typedef __attribute__((ext_vector_type(8))) __bf16 bf16x8;
typedef __attribute__((ext_vector_type(4))) float f32x4;
typedef __attribute__((ext_vector_type(8))) unsigned short ushort8;

// RNE f32->bf16 via native cast: compiler emits v_cvt_pk_bf16_f32 (1 op / 2 elems)
__device__ __forceinline__ unsigned short f2bf(float f) {
    __bf16 h = (__bf16)f;
    return __builtin_bit_cast(unsigned short, h);
}
__device__ __forceinline__ float bf2f(unsigned short h) {
    return __uint_as_float(((unsigned int)h) << 16);
}
__device__ __forceinline__ void gload_lds16(const unsigned short* g, unsigned short* l) {
    __builtin_amdgcn_global_load_lds(
        (const __attribute__((address_space(1))) unsigned int*)g,
        (__attribute__((address_space(3))) unsigned int*)l, 16, 0, 0);
}
__device__ __forceinline__ bf16x8 ldfrag(const unsigned short* p) {
    ushort8 t = *(const ushort8*)p;
    return __builtin_bit_cast(bf16x8, t);
}

// ---- fused prep: U^T (bf16), W^T (bf16), V convert (bf16), one launch ----
__global__ void prep(const float* __restrict__ U, const float* __restrict__ W,
                     const float* __restrict__ V,
                     unsigned short* __restrict__ UT, unsigned short* __restrict__ WT,
                     unsigned short* __restrict__ Vb) {
    __shared__ unsigned short t[64][66];
    int bid = blockIdx.x, tid = threadIdx.x;
    if (bid < 288) {
        const float* src; unsigned short* dst; int R, C, rb, cb;
        if (bid < 256) { src = U; dst = UT; R = N_IN; C = RANK; rb = (bid & 63) * 64; cb = (bid >> 6) * 64; }
        else { int b = bid - 256; src = W; dst = WT; R = N_CTX; C = RANK; rb = (b & 7) * 64; cb = (b >> 3) * 64; }
        int r = tid >> 4, c4 = (tid & 15) * 4;
        for (int i = 0; i < 4; i++) {
            float4 v = *(const float4*)(src + (size_t)(rb + r + i * 16) * C + cb + c4);
            t[r + i * 16][c4 + 0] = f2bf(v.x);
            t[r + i * 16][c4 + 1] = f2bf(v.y);
            t[r + i * 16][c4 + 2] = f2bf(v.z);
            t[r + i * 16][c4 + 3] = f2bf(v.w);
        }
        __syncthreads();
        int c = tid >> 3, r8 = (tid & 7) * 8;
        for (int j = 0; j < 2; j++) {
            int cc = c + j * 32;
            ushort8 o;
            for (int k = 0; k < 8; k++) o[k] = t[r8 + k][cc];
            *(ushort8*)(dst + (size_t)(cb + cc) * R + rb + r8) = o;
        }
    } else {
        size_t base = (size_t)(bid - 288) * 2048 + (size_t)tid * 8;
        float4 a = *(const float4*)(V + base);
        float4 b = *(const float4*)(V + base + 4);
        ushort8 o = { f2bf(a.x), f2bf(a.y), f2bf(a.z), f2bf(a.w),
                      f2bf(b.x), f2bf(b.y), f2bf(b.z), f2bf(b.w) };
        *(ushort8*)(Vb + base) = o;
    }
}

// All GEMM tiles (k21): rows of 64 bf16 = 128B = 8 chunks of 16B.
// LDS slot (row, cs) holds data chunk cs^(row&7)  -> bank-balanced b128 access.

// ---- K21: fused launch. blocks 0..511: k2 (T0p partials); 512..767: 2x k1 tiles ----
__launch_bounds__(512, 2)
__global__ void k21(const float* __restrict__ X, const unsigned short* __restrict__ UT,
                    unsigned short* __restrict__ T0p,
                    const float* __restrict__ ctx, const unsigned short* __restrict__ WT,
                    const float* __restrict__ S, const float* __restrict__ Bb,
                    unsigned short* __restrict__ Schi) {
    __shared__ char smem[49152];
    int tid = threadIdx.x, bfull = blockIdx.x;
    int w = tid >> 6, lane = tid & 63;
    int ln15 = lane & 15, quad = lane >> 4;
    if (bfull < 512) {
        // ---------------- k2 ----------------
        int z = bfull >> 5, my = bfull & 31;
        unsigned short* As = (unsigned short*)smem;          // 128*64 = 16KB
        unsigned short* Bs = As + 128 * 64;                  // 256*64 = 32KB
        int wr = w >> 2, wc = w & 3;                         // 2 x 4 wave grid
        int tm = my * 128;
        int kbase = z * (N_IN / ZSPLIT);
        f32x4 acc[4][4] = {};
        int arow = tid >> 2, acs0 = (tid & 3) * 2;           // A: 2 chunks/thread (16 f32)
        const float* ag = X + (size_t)(tm + arow) * N_IN + kbase + acs0 * 8;
        unsigned short* al0 = As + arow * 64 + ((acs0 + 0) ^ (arow & 7)) * 8;
        unsigned short* al1 = As + arow * 64 + ((acs0 + 1) ^ (arow & 7)) * 8;
        int bl8 = lane >> 3, bcs = lane & 7;
        int bgc = (bcs ^ bl8) * 8;
        for (int kt = 0; kt < (N_IN / ZSPLIT) / 64; kt++) {
            int k0 = kt * 64;
            for (int c = 0; c < 4; c++) {
                int row = w * 32 + c * 8 + bl8;              // rows 0..255 = full RANK
                gload_lds16(UT + (size_t)row * N_IN + kbase + k0 + bgc, Bs + row * 64 + bcs * 8);
            }
            {
                float4 v0 = *(const float4*)(ag + k0);
                float4 v1 = *(const float4*)(ag + k0 + 4);
                float4 u0 = *(const float4*)(ag + k0 + 8);
                float4 u1 = *(const float4*)(ag + k0 + 12);
                ushort8 a8 = { f2bf(v0.x), f2bf(v0.y), f2bf(v0.z), f2bf(v0.w),
                               f2bf(v1.x), f2bf(v1.y), f2bf(v1.z), f2bf(v1.w) };
                ushort8 b8 = { f2bf(u0.x), f2bf(u0.y), f2bf(u0.z), f2bf(u0.w),
                               f2bf(u1.x), f2bf(u1.y), f2bf(u1.z), f2bf(u1.w) };
                *(ushort8*)al0 = a8;
                *(ushort8*)al1 = b8;
            }
            __syncthreads();
            for (int kh = 0; kh < 2; kh++) {
                int ch = kh * 4 + quad;
                int sw = (ch ^ (ln15 & 7)) * 8;
                bf16x8 af[4];
                for (int i = 0; i < 4; i++)
                    af[i] = ldfrag(As + (wr * 64 + i * 16 + ln15) * 64 + sw);
                for (int j = 0; j < 4; j++) {
                    bf16x8 b = ldfrag(Bs + (wc * 64 + j * 16 + ln15) * 64 + sw);
                    for (int i = 0; i < 4; i++)
                        acc[i][j] = __builtin_amdgcn_mfma_f32_16x16x32_bf16(af[i], b, acc[i][j], 0, 0, 0);
                }
            }
            __syncthreads();
        }
        // epilogue: stage 64-row halves through LDS, store coalesced ushort8
        unsigned short* P = T0p + (size_t)z * B_SZ * RANK;
        unsigned short* ep = (unsigned short*)smem;
        const int EPW = 280;
        int er = tid >> 3, ec0 = tid & 7;
        for (int h = 0; h < 2; h++) {
            if (wr == h) {
                for (int i = 0; i < 4; i++)
                    for (int j = 0; j < 4; j++)
                        for (int r = 0; r < 4; r++)
                            ep[(i * 16 + quad * 4 + r) * EPW + wc * 64 + j * 16 + ln15] = f2bf(acc[i][j][r]);
            }
            __syncthreads();
            for (int k = 0; k < 4; k++) {
                int chunk = ec0 + 8 * k;
                *(ushort8*)(P + (size_t)(tm + h * 64 + er) * RANK + chunk * 8) =
                    *(const ushort8*)(ep + er * EPW + chunk * 8);
            }
            __syncthreads();
        }
    } else {
        // ---------------- k1 (two 32x64 tiles per block) ----------------
        int hh = tid >> 8;
        int sb = (bfull - 512) * 2 + hh;
        int bx = sb & 3, by = sb >> 2;
        int t = tid & 255;
        int lw = t >> 6, llane = t & 63;
        int lln15 = llane & 15, lquad = llane >> 4;
        int wr = lw >> 1, wc = lw & 1;
        unsigned short* base = (unsigned short*)smem + hh * 6144;
        unsigned short* As = base;
        unsigned short* Bs = base + 32 * 64;
        int tm = by * 32, tn = bx * 64;
        f32x4 acc2[2] = {};
        int arow = t >> 3, acs = t & 7;
        const float* ag = ctx + (size_t)(tm + arow) * N_CTX + acs * 8;
        unsigned short* al = As + arow * 64 + (acs ^ (arow & 7)) * 8;
        int bl8 = llane >> 3, bcs = llane & 7;
        int bgc = (bcs ^ bl8) * 8;
        for (int kt = 0; kt < 8; kt++) {
            int k0 = kt * 64;
            for (int c = 0; c < 2; c++) {
                int row = lw * 16 + c * 8 + bl8;
                gload_lds16(WT + (size_t)(tn + row) * N_CTX + k0 + bgc, Bs + row * 64 + bcs * 8);
            }
            {
                float4 v0 = *(const float4*)(ag + k0);
                float4 v1 = *(const float4*)(ag + k0 + 4);
                ushort8 a8 = { f2bf(v0.x), f2bf(v0.y), f2bf(v0.z), f2bf(v0.w),
                               f2bf(v1.x), f2bf(v1.y), f2bf(v1.z), f2bf(v1.w) };
                *(ushort8*)al = a8;
            }
            __syncthreads();
            for (int kh = 0; kh < 2; kh++) {
                int ch = kh * 4 + lquad;
                bf16x8 af = ldfrag(As + (wr * 16 + lln15) * 64 + (ch ^ (lln15 & 7)) * 8);
                for (int j = 0; j < 2; j++) {
                    int row = wc * 32 + j * 16 + lln15;
                    bf16x8 bfr = ldfrag(Bs + row * 64 + (ch ^ (lln15 & 7)) * 8);
                    acc2[j] = __builtin_amdgcn_mfma_f32_16x16x32_bf16(af, bfr, acc2[j], 0, 0, 0);
                }
            }
            __syncthreads();
        }
        for (int j = 0; j < 2; j++) {
            int col = tn + wc * 32 + j * 16 + lln15;
            float sv = S[col], bv = Bb[col];
            for (int r = 0; r < 4; r++) {
                int row = tm + wr * 16 + lquad * 4 + r;
                float x = acc2[j][r] + bv;
                float chi = sv / (1.f + __expf(-x));
                Schi[(size_t)row * RANK + col] = f2bf(chi);
            }
        }
    }
}

// ---- E: T = bf16( (sum_z T0p[z]) * Schi ) ------------------------------
__global__ void e_red(const unsigned short* __restrict__ T0p, const unsigned short* __restrict__ Schi,
                      unsigned short* __restrict__ T) {
    int i = blockIdx.x * 256 + threadIdx.x;   // ushort8 index
    const size_t stride = (size_t)B_SZ * RANK;
    float a[8] = {};
    for (int z = 0; z < ZSPLIT; z++) {
        ushort8 p = *(const ushort8*)(T0p + z * stride + (size_t)i * 8);
        for (int k = 0; k < 8; k++) a[k] += bf2f(p[k]);
    }
    ushort8 s = *(const ushort8*)(Schi + (size_t)i * 8);
    ushort8 o;
    for (int k = 0; k < 8; k++) o[k] = f2bf(a[k] * bf2f(s[k]));
    *(ushort8*)(T + (size_t)i * 8) = o;
}

// ---- K3: out = relu(T @ V^T + 2*bias) ---------------------------------
// NEW STRUCTURE: grid (32 n-chunks x 8 m-groups) = 256 blocks, 512 thr, 1 blk/CU.
// B panel (128 Vb-rows x FULL K=256 = 64KB) resident in LDS for the whole block.
// Long m-loop: 8 steps x 64 rows; A double-buffered via global_load_lds with
// raw s_barrier + counted vmcnt(4) so the next A-tile stays in flight across
// the barrier. Dedicated 32KB LDS epilogue buffer -> coalesced float4 stores.
// LDS rows are 256 bf16 = 512B = 32 chunks of 16B; slot c16 holds data chunk
// (c16&24)|((c16&7)^(row&7))  (XOR within 8-chunk groups, involution).
__launch_bounds__(512, 1)
__global__ void k3_out(const unsigned short* __restrict__ T, const unsigned short* __restrict__ Vb,
                       const float* __restrict__ bias, float* __restrict__ out) {
    __shared__ char smem[163840];                          // 64KB B + 2x32KB A + 32KB ep
    unsigned short* Bs = (unsigned short*)smem;            // [128][256]
    unsigned short* A0 = (unsigned short*)(smem + 65536);  // [64][256]
    unsigned short* A1 = A0 + 64 * 256;                    // [64][256]
    float* ep = (float*)(smem + 131072);                   // [64][128]
    int tid = threadIdx.x, w = tid >> 6, lane = tid & 63;
    int ln15 = lane & 15, quad = lane >> 4;
    int wr = w >> 2, wc = w & 3;                           // 2 m-halves x 4 n-quarters
    int tn = blockIdx.x * 128;
    int tmg = blockIdx.y * 512;
    int lr2 = lane >> 5, lc16 = lane & 31;                 // within one 1KB wave-load

    // stage full B panel once: Vb rows tn..tn+127, all 256 k
    for (int i = 0; i < 8; i++) {
        int row = (w * 8 + i) * 2 + lr2;
        int g = (lc16 & 24) | ((lc16 & 7) ^ (row & 7));
        gload_lds16(Vb + (size_t)(tn + row) * RANK + g * 8, Bs + row * 256 + lc16 * 8);
    }
#define STAGE_A3(buf, step) do { \
    for (int i = 0; i < 4; i++) { \
        int row = (w * 4 + i) * 2 + lr2; \
        int g = (lc16 & 24) | ((lc16 & 7) ^ (row & 7)); \
        gload_lds16(T + (size_t)(tmg + (step) * 64 + row) * RANK + g * 8, \
                    (buf) + row * 256 + lc16 * 8); \
    } } while (0)
    STAGE_A3(A0, 0);
    float bv0 = 2.f * bias[tn + wc * 32 + ln15];
    float bv1 = 2.f * bias[tn + wc * 32 + 16 + ln15];
    unsigned short* cur = A0;
    unsigned short* nxt = A1;
    for (int t = 0; t < 8; t++) {
        STAGE_A3(nxt, (t + 1) & 7);                        // wrap-issue; keeps vmcnt uniform
        asm volatile("s_waitcnt vmcnt(4)" ::: "memory");   // A(t) [and B on t=0] landed
        __builtin_amdgcn_s_barrier();
        __builtin_amdgcn_sched_barrier(0);
        f32x4 acc[2][2] = {};
        for (int kh = 0; kh < 8; kh++) {
            int c = kh * 4 + quad;
            bf16x8 af[2], bf[2];
            for (int i = 0; i < 2; i++) {
                int row = wr * 32 + i * 16 + ln15;
                int c16 = (c & 24) | ((c & 7) ^ (row & 7));
                af[i] = ldfrag(cur + row * 256 + c16 * 8);
            }
            for (int j = 0; j < 2; j++) {
                int row = wc * 32 + j * 16 + ln15;
                int c16 = (c & 24) | ((c & 7) ^ (row & 7));
                bf[j] = ldfrag(Bs + row * 256 + c16 * 8);
            }
            for (int i = 0; i < 2; i++)
                for (int j = 0; j < 2; j++)
                    acc[i][j] = __builtin_amdgcn_mfma_f32_16x16x32_bf16(af[i], bf[j], acc[i][j], 0, 0, 0);
        }
        // epilogue: bias+relu -> ep (all waves), then coalesced float4 stores
        for (int i = 0; i < 2; i++)
            for (int j = 0; j < 2; j++) {
                float bv = j ? bv1 : bv0;
                for (int r = 0; r < 4; r++)
                    ep[(wr * 32 + i * 16 + quad * 4 + r) * 128 + wc * 32 + j * 16 + ln15] =
                        fmaxf(acc[i][j][r] + bv, 0.f);
            }
        asm volatile("s_waitcnt lgkmcnt(0)" ::: "memory");
        __builtin_amdgcn_s_barrier();
        __builtin_amdgcn_sched_barrier(0);
        {
            int er = tid >> 3, ec = tid & 7;
            size_t orow = (size_t)(tmg + t * 64 + er) * UNITS + tn;
            for (int k = 0; k < 4; k++)
                *(float4*)(out + orow + (ec + k * 8) * 4) =
                    *(const float4*)(ep + er * 128 + (ec + k * 8) * 4);
        }
        __builtin_amdgcn_s_barrier();                      // ep + cur-buf safe to reuse
        unsigned short* tmp = cur; cur = nxt; nxt = tmp;
    }
#undef STAGE_A3
}

extern "C" void kernel_launch(void* const* d_in, const int* in_sizes, int n_in,
                              void* d_out, int out_size, void* d_ws, size_t ws_size,
                              hipStream_t stream) {
    (void)in_sizes; (void)n_in; (void)out_size; (void)ws_size;
    const float* inputs  = (const float*)d_in[0];
    const float* context = (const float*)d_in[1];
    const float* U       = (const float*)d_in[2];
    const float* S       = (const float*)d_in[3];
    const float* V       = (const float*)d_in[4];
    const float* W       = (const float*)d_in[5];
    const float* Bb      = (const float*)d_in[6];
    const float* bias    = (const float*)d_in[7];
    float* out = (float*)d_out;

    char* ws = (char*)d_ws;
    size_t o = 0;
    unsigned short* UT   = (unsigned short*)(ws + o); o += (size_t)RANK * N_IN * 2;
    unsigned short* WT   = (unsigned short*)(ws + o); o += (size_t)RANK * N_CTX * 2;
    unsigned short* Vb   = (unsigned short*)(ws + o); o += (size_t)UNITS * RANK * 2;
    unsigned short* Schi = (unsigned short*)(ws + o); o += (size_t)B_SZ * RANK * 2;
    unsigned short* T    = (unsigned short*)(ws + o); o += (size_t)B_SZ * RANK * 2;
    unsigned short* T0p  = (unsigned short*)(ws + o); o += (size_t)ZSPLIT * B_SZ * RANK * 2;

    prep<<<800, 256, 0, stream>>>(U, W, V, UT, WT, Vb);
    k21<<<768, 512, 0, stream>>>(inputs, UT, T0p, context, WT, S, Bb, Schi);
    e_red<<<(B_SZ * RANK) / (256 * 8), 256, 0, stream>>>(T0p, Schi, T);
    k3_out<<<dim3(32, 8), 512, 0, stream>>>(T, Vb, bias, out);
}

// Round 9
// 170.225 us; speedup vs baseline: 1.0369x; 1.0369x over previous
//
#include <hip/hip_runtime.h>

#define B_SZ 4096
#define N_IN 4096
#define N_CTX 512
#define UNITS 4096
#define RANK 256
#define ZSPLIT 8

typedef __attribute__((ext_vector_type(8))) __bf16 bf16x8;
typedef __attribute__((ext_vector_type(4))) float f32x4;
typedef __attribute__((ext_vector_type(8))) unsigned short ushort8;

// RNE f32->bf16 via native cast: compiler emits v_cvt_pk_bf16_f32 (1 op / 2 elems)
__device__ __forceinline__ unsigned short f2bf(float f) {
    __bf16 h = (__bf16)f;
    return __builtin_bit_cast(unsigned short, h);
}
__device__ __forceinline__ float bf2f(unsigned short h) {
    return __uint_as_float(((unsigned int)h) << 16);
}
__device__ __forceinline__ void gload_lds16(const unsigned short* g, unsigned short* l) {
    __builtin_amdgcn_global_load_lds(
        (const __attribute__((address_space(1))) unsigned int*)g,
        (__attribute__((address_space(3))) unsigned int*)l, 16, 0, 0);
}
__device__ __forceinline__ bf16x8 ldfrag(const unsigned short* p) {
    ushort8 t = *(const ushort8*)p;
    return __builtin_bit_cast(bf16x8, t);
}
// inline-asm f32x4 load: pinned issue order + manual vmcnt accounting.
// NOTE: compiler does NOT model this op's vmcnt -- every read of the dest
// must be preceded by a manual s_waitcnt AND sched_barrier(0) (rule #18).
__device__ __forceinline__ void gld4(float4& d, const float* p) {
    asm volatile("global_load_dwordx4 %0, %1, off" : "=v"(d) : "v"(p) : "memory");
}

// ---- fused prep: U^T (bf16), W^T (bf16), V convert (bf16), one launch ----
__global__ void prep(const float* __restrict__ U, const float* __restrict__ W,
                     const float* __restrict__ V,
                     unsigned short* __restrict__ UT, unsigned short* __restrict__ WT,
                     unsigned short* __restrict__ Vb) {
    __shared__ unsigned short t[64][66];
    int bid = blockIdx.x, tid = threadIdx.x;
    if (bid < 288) {
        const float* src; unsigned short* dst; int R, C, rb, cb;
        if (bid < 256) { src = U; dst = UT; R = N_IN; C = RANK; rb = (bid & 63) * 64; cb = (bid >> 6) * 64; }
        else { int b = bid - 256; src = W; dst = WT; R = N_CTX; C = RANK; rb = (b & 7) * 64; cb = (b >> 3) * 64; }
        int r = tid >> 4, c4 = (tid & 15) * 4;
        for (int i = 0; i < 4; i++) {
            float4 v = *(const float4*)(src + (size_t)(rb + r + i * 16) * C + cb + c4);
            t[r + i * 16][c4 + 0] = f2bf(v.x);
            t[r + i * 16][c4 + 1] = f2bf(v.y);
            t[r + i * 16][c4 + 2] = f2bf(v.z);
            t[r + i * 16][c4 + 3] = f2bf(v.w);
        }
        __syncthreads();
        int c = tid >> 3, r8 = (tid & 7) * 8;
        for (int j = 0; j < 2; j++) {
            int cc = c + j * 32;
            ushort8 o;
            for (int k = 0; k < 8; k++) o[k] = t[r8 + k][cc];
            *(ushort8*)(dst + (size_t)(cb + cc) * R + rb + r8) = o;
        }
    } else {
        size_t base = (size_t)(bid - 288) * 2048 + (size_t)tid * 8;
        float4 a = *(const float4*)(V + base);
        float4 b = *(const float4*)(V + base + 4);
        ushort8 o = { f2bf(a.x), f2bf(a.y), f2bf(a.z), f2bf(a.w),
                      f2bf(b.x), f2bf(b.y), f2bf(b.z), f2bf(b.w) };
        *(ushort8*)(Vb + base) = o;
    }
}

// ---- K21 fused. blocks 0..255: k2 pipelined; 256..511: 2x k1 tiles ----
// k2: T0p[z] = X@U partial. tile 128x256 (full RANK), 512 thr (2x4 waves),
//     BK=64, K-slice 512 (8 steps), grid m32 x z8.
//     B (UT) triple-buffered global_load_lds (issue t -> consume t+2);
//     A (f32 X) dual reg-set asm loads (issue t -> ds_write end of t+1) +
//     double LDS buffer. One raw s_barrier/step, vmcnt(8) counted (never 0
//     mid-loop), lgkmcnt(0) only for the A ds_write. LDS 128KB, 1 blk/CU.
__launch_bounds__(512, 1)
__global__ void k21(const float* __restrict__ X, const unsigned short* __restrict__ UT,
                    unsigned short* __restrict__ T0p,
                    const float* __restrict__ ctx, const unsigned short* __restrict__ WT,
                    const float* __restrict__ S, const float* __restrict__ Bb,
                    unsigned short* __restrict__ Schi) {
    __shared__ char smem[131072];
    int tid = threadIdx.x, bfull = blockIdx.x;
    int w = tid >> 6, lane = tid & 63;
    int ln15 = lane & 15, quad = lane >> 4;
    if (bfull < 256) {
        // ---------------- k2 ----------------
        int mblk = bfull & 31, z = bfull >> 5;
        unsigned short* Bs = (unsigned short*)smem;          // 3 x [256][64] = 96KB
        unsigned short* Al = Bs + 3 * 256 * 64;              // 2 x [128][64] = 32KB
        int wr = w >> 2, wc = w & 3;                         // 2m x 4n waves
        int tm = mblk * 128;
        int kbase = z * (N_IN / ZSPLIT);                     // z*512
        f32x4 acc[4][4] = {};
        int bl8 = lane >> 3, bcs = lane & 7;
        int bgc = (bcs ^ bl8) * 8;                           // B swizzled global chunk
        int arow = tid >> 2, acs0 = (tid & 3) * 2;           // A: 2 chunks (16 f32)/thread
        const float* ag = X + (size_t)(tm + arow) * N_IN + kbase + acs0 * 8;
        int aoff0 = arow * 64 + ((acs0 + 0) ^ (arow & 7)) * 8;
        int aoff1 = arow * 64 + ((acs0 + 1) ^ (arow & 7)) * 8;
        float4 ra[2][4];                                     // [set][quarter]

#define K2_B_STAGE(buf, k0) do { \
    for (int c = 0; c < 4; c++) { \
        int row = w * 32 + c * 8 + bl8; \
        gload_lds16(UT + (size_t)row * N_IN + kbase + (k0) + bgc, \
                    Bs + (buf) * 16384 + row * 64 + bcs * 8); \
    } } while (0)
#define K2_A_ISSUE(set, k0) do { \
    gld4(ra[set][0], ag + (k0)); \
    gld4(ra[set][1], ag + (k0) + 4); \
    gld4(ra[set][2], ag + (k0) + 8); \
    gld4(ra[set][3], ag + (k0) + 12); } while (0)
#define K2_A_WRITE(set, buf) do { \
    float4 x0 = ra[set][0], x1 = ra[set][1], x2 = ra[set][2], x3 = ra[set][3]; \
    ushort8 o0 = { f2bf(x0.x), f2bf(x0.y), f2bf(x0.z), f2bf(x0.w), \
                   f2bf(x1.x), f2bf(x1.y), f2bf(x1.z), f2bf(x1.w) }; \
    ushort8 o1 = { f2bf(x2.x), f2bf(x2.y), f2bf(x2.z), f2bf(x2.w), \
                   f2bf(x3.x), f2bf(x3.y), f2bf(x3.z), f2bf(x3.w) }; \
    *(ushort8*)(Al + (buf) * 8192 + aoff0) = o0; \
    *(ushort8*)(Al + (buf) * 8192 + aoff1) = o1; } while (0)
#define WAITV(n) do { \
    asm volatile("s_waitcnt vmcnt(" #n ")" ::: "memory"); \
    __builtin_amdgcn_sched_barrier(0); } while (0)
#define WAITL0 do { \
    asm volatile("s_waitcnt lgkmcnt(0)" ::: "memory"); \
    __builtin_amdgcn_sched_barrier(0); } while (0)

        // prologue: out-FIFO = [A0,B0,B1]
        K2_A_ISSUE(0, 0);
        K2_B_STAGE(0, 0);
        K2_B_STAGE(1, 64);
        WAITV(8);                                            // A0 landed
        K2_A_WRITE(0, 0);
        K2_A_ISSUE(1, 64);                                   // FIFO = [B0,B1,A1]
        WAITV(8);                                            // B0 landed
        WAITL0;                                              // A0 ds_write done
        __builtin_amdgcn_s_barrier();
        __builtin_amdgcn_sched_barrier(0);

#pragma unroll
        for (int t = 0; t < 8; t++) {
            if (t + 2 < 8) {
                K2_A_ISSUE(t & 1, (t + 2) * 64);             // overwrites consumed set
                K2_B_STAGE((t + 2) % 3, (t + 2) * 64);       // FIFO = [B(t+1),A(t+1),A(t+2),B(t+2)]
            }
            __builtin_amdgcn_s_setprio(1);
#pragma unroll
            for (int kh = 0; kh < 2; kh++) {
                int ch = kh * 4 + quad;
                int sw = (ch ^ (ln15 & 7)) * 8;
                bf16x8 af[4];
#pragma unroll
                for (int i = 0; i < 4; i++)
                    af[i] = ldfrag(Al + (t & 1) * 8192 + (wr * 64 + i * 16 + ln15) * 64 + sw);
#pragma unroll
                for (int j = 0; j < 4; j++) {
                    bf16x8 b = ldfrag(Bs + (t % 3) * 16384 + (wc * 64 + j * 16 + ln15) * 64 + sw);
#pragma unroll
                    for (int i = 0; i < 4; i++)
                        acc[i][j] = __builtin_amdgcn_mfma_f32_16x16x32_bf16(af[i], b, acc[i][j], 0, 0, 0);
                }
            }
            __builtin_amdgcn_s_setprio(0);
            if (t < 7) {
                if (t + 2 < 8) {
                    WAITV(8);                                // B(t+1),A(t+1) landed
                } else {
                    WAITV(0);                                // tail drain (A7,B7)
                }
                K2_A_WRITE((t + 1) & 1, (t + 1) & 1);
                WAITL0;
                __builtin_amdgcn_s_barrier();
                __builtin_amdgcn_sched_barrier(0);
            }
        }
#undef K2_B_STAGE
#undef K2_A_ISSUE
#undef K2_A_WRITE
#undef WAITV
#undef WAITL0
        // epilogue: stage 64-row halves through LDS, store coalesced ushort8
        __syncthreads();
        unsigned short* P = T0p + (size_t)z * B_SZ * RANK;
        unsigned short* ep = (unsigned short*)smem;
        const int EPW = 280;
        int er = tid >> 3, ec0 = tid & 7;
        for (int h = 0; h < 2; h++) {
            if (wr == h) {
                for (int i = 0; i < 4; i++)
                    for (int j = 0; j < 4; j++)
                        for (int r = 0; r < 4; r++)
                            ep[(i * 16 + quad * 4 + r) * EPW + wc * 64 + j * 16 + ln15] = f2bf(acc[i][j][r]);
            }
            __syncthreads();
            for (int k = 0; k < 4; k++) {
                int chunk = ec0 + 8 * k;
                *(ushort8*)(P + (size_t)(tm + h * 64 + er) * RANK + chunk * 8) =
                    *(const ushort8*)(ep + er * EPW + chunk * 8);
            }
            __syncthreads();
        }
    } else {
        // ---------------- k1 (two 32x64 tiles per block) ----------------
        int hh = tid >> 8;
        int sb = (bfull - 256) * 2 + hh;
        int bx = sb & 3, by = sb >> 2;
        int t = tid & 255;
        int lw = t >> 6, llane = t & 63;
        int lln15 = llane & 15, lquad = llane >> 4;
        int wr = lw >> 1, wc = lw & 1;
        unsigned short* base = (unsigned short*)smem + hh * 6144;
        unsigned short* As = base;
        unsigned short* Bs = base + 32 * 64;
        int tm = by * 32, tn = bx * 64;
        f32x4 acc2[2] = {};
        int arow = t >> 3, acs = t & 7;
        const float* ag = ctx + (size_t)(tm + arow) * N_CTX + acs * 8;
        unsigned short* al = As + arow * 64 + (acs ^ (arow & 7)) * 8;
        int bl8 = llane >> 3, bcs = llane & 7;
        int bgc = (bcs ^ bl8) * 8;
        for (int kt = 0; kt < 8; kt++) {
            int k0 = kt * 64;
            for (int c = 0; c < 2; c++) {
                int row = lw * 16 + c * 8 + bl8;
                gload_lds16(WT + (size_t)(tn + row) * N_CTX + k0 + bgc, Bs + row * 64 + bcs * 8);
            }
            {
                float4 v0 = *(const float4*)(ag + k0);
                float4 v1 = *(const float4*)(ag + k0 + 4);
                ushort8 a8 = { f2bf(v0.x), f2bf(v0.y), f2bf(v0.z), f2bf(v0.w),
                               f2bf(v1.x), f2bf(v1.y), f2bf(v1.z), f2bf(v1.w) };
                *(ushort8*)al = a8;
            }
            __syncthreads();
            for (int kh = 0; kh < 2; kh++) {
                int ch = kh * 4 + lquad;
                bf16x8 af = ldfrag(As + (wr * 16 + lln15) * 64 + (ch ^ (lln15 & 7)) * 8);
                for (int j = 0; j < 2; j++) {
                    int row = wc * 32 + j * 16 + lln15;
                    bf16x8 bfr = ldfrag(Bs + row * 64 + (ch ^ (lln15 & 7)) * 8);
                    acc2[j] = __builtin_amdgcn_mfma_f32_16x16x32_bf16(af, bfr, acc2[j], 0, 0, 0);
                }
            }
            __syncthreads();
        }
        for (int j = 0; j < 2; j++) {
            int col = tn + wc * 32 + j * 16 + lln15;
            float sv = S[col], bv = Bb[col];
            for (int r = 0; r < 4; r++) {
                int row = tm + wr * 16 + lquad * 4 + r;
                float x = acc2[j][r] + bv;
                float chi = sv / (1.f + __expf(-x));
                Schi[(size_t)row * RANK + col] = f2bf(chi);
            }
        }
    }
}

// ---- E: T = bf16( (sum_z T0p[z]) * Schi ) ------------------------------
__global__ void e_red(const unsigned short* __restrict__ T0p, const unsigned short* __restrict__ Schi,
                      unsigned short* __restrict__ T) {
    int i = blockIdx.x * 256 + threadIdx.x;   // ushort8 index
    const size_t stride = (size_t)B_SZ * RANK;
    float a[8] = {};
    for (int z = 0; z < ZSPLIT; z++) {
        ushort8 p = *(const ushort8*)(T0p + z * stride + (size_t)i * 8);
        for (int k = 0; k < 8; k++) a[k] += bf2f(p[k]);
    }
    ushort8 s = *(const ushort8*)(Schi + (size_t)i * 8);
    ushort8 o;
    for (int k = 0; k < 8; k++) o[k] = f2bf(a[k] * bf2f(s[k]));
    *(ushort8*)(T + (size_t)i * 8) = o;
}

// ---- K3: out = relu(T @ V^T + 2*bias) ---------------------------------
// grid (32 n-chunks x 8 m-groups) = 256 blocks, 512 thr, 1 blk/CU.
// B panel (128 Vb-rows x full K=256 = 64KB) LDS-resident; 8-step m-loop,
// A dbuf via global_load_lds, raw s_barrier + counted vmcnt(4).
__launch_bounds__(512, 1)
__global__ void k3_out(const unsigned short* __restrict__ T, const unsigned short* __restrict__ Vb,
                       const float* __restrict__ bias, float* __restrict__ out) {
    __shared__ char smem[163840];                          // 64KB B + 2x32KB A + 32KB ep
    unsigned short* Bs = (unsigned short*)smem;            // [128][256]
    unsigned short* A0 = (unsigned short*)(smem + 65536);  // [64][256]
    unsigned short* A1 = A0 + 64 * 256;                    // [64][256]
    float* ep = (float*)(smem + 131072);                   // [64][128]
    int tid = threadIdx.x, w = tid >> 6, lane = tid & 63;
    int ln15 = lane & 15, quad = lane >> 4;
    int wr = w >> 2, wc = w & 3;                           // 2 m-halves x 4 n-quarters
    int tn = blockIdx.x * 128;
    int tmg = blockIdx.y * 512;
    int lr2 = lane >> 5, lc16 = lane & 31;                 // within one 1KB wave-load

    // stage full B panel once: Vb rows tn..tn+127, all 256 k
    for (int i = 0; i < 8; i++) {
        int row = (w * 8 + i) * 2 + lr2;
        int g = (lc16 & 24) | ((lc16 & 7) ^ (row & 7));
        gload_lds16(Vb + (size_t)(tn + row) * RANK + g * 8, Bs + row * 256 + lc16 * 8);
    }
#define STAGE_A3(buf, step) do { \
    for (int i = 0; i < 4; i++) { \
        int row = (w * 4 + i) * 2 + lr2; \
        int g = (lc16 & 24) | ((lc16 & 7) ^ (row & 7)); \
        gload_lds16(T + (size_t)(tmg + (step) * 64 + row) * RANK + g * 8, \
                    (buf) + row * 256 + lc16 * 8); \
    } } while (0)
    STAGE_A3(A0, 0);
    float bv0 = 2.f * bias[tn + wc * 32 + ln15];
    float bv1 = 2.f * bias[tn + wc * 32 + 16 + ln15];
    unsigned short* cur = A0;
    unsigned short* nxt = A1;
    for (int t = 0; t < 8; t++) {
        STAGE_A3(nxt, (t + 1) & 7);                        // wrap-issue; uniform vmcnt
        asm volatile("s_waitcnt vmcnt(4)" ::: "memory");   // A(t) [and B on t=0] landed
        __builtin_amdgcn_s_barrier();
        __builtin_amdgcn_sched_barrier(0);
        f32x4 acc[2][2] = {};
        for (int kh = 0; kh < 8; kh++) {
            int c = kh * 4 + quad;
            bf16x8 af[2], bf[2];
            for (int i = 0; i < 2; i++) {
                int row = wr * 32 + i * 16 + ln15;
                int c16 = (c & 24) | ((c & 7) ^ (row & 7));
                af[i] = ldfrag(cur + row * 256 + c16 * 8);
            }
            for (int j = 0; j < 2; j++) {
                int row = wc * 32 + j * 16 + ln15;
                int c16 = (c & 24) | ((c & 7) ^ (row & 7));
                bf[j] = ldfrag(Bs + row * 256 + c16 * 8);
            }
            for (int i = 0; i < 2; i++)
                for (int j = 0; j < 2; j++)
                    acc[i][j] = __builtin_amdgcn_mfma_f32_16x16x32_bf16(af[i], bf[j], acc[i][j], 0, 0, 0);
        }
        // epilogue: bias+relu -> ep, then coalesced float4 stores
        for (int i = 0; i < 2; i++)
            for (int j = 0; j < 2; j++) {
                float bv = j ? bv1 : bv0;
                for (int r = 0; r < 4; r++)
                    ep[(wr * 32 + i * 16 + quad * 4 + r) * 128 + wc * 32 + j * 16 + ln15] =
                        fmaxf(acc[i][j][r] + bv, 0.f);
            }
        asm volatile("s_waitcnt lgkmcnt(0)" ::: "memory");
        __builtin_amdgcn_s_barrier();
        __builtin_amdgcn_sched_barrier(0);
        {
            int er = tid >> 3, ec = tid & 7;
            size_t orow = (size_t)(tmg + t * 64 + er) * UNITS + tn;
            for (int k = 0; k < 4; k++)
                *(float4*)(out + orow + (ec + k * 8) * 4) =
                    *(const float4*)(ep + er * 128 + (ec + k * 8) * 4);
        }
        __builtin_amdgcn_s_barrier();                      // ep + cur-buf safe to reuse
        unsigned short* tmp = cur; cur = nxt; nxt = tmp;
    }
#undef STAGE_A3
}

extern "C" void kernel_launch(void* const* d_in, const int* in_sizes, int n_in,
                              void* d_out, int out_size, void* d_ws, size_t ws_size,
                              hipStream_t stream) {
    (void)in_sizes; (void)n_in; (void)out_size; (void)ws_size;
    const float* inputs  = (const float*)d_in[0];
    const float* context = (const float*)d_in[1];
    const float* U       = (const float*)d_in[2];
    const float* S       = (const float*)d_in[3];
    const float* V       = (const float*)d_in[4];
    const float* W       = (const float*)d_in[5];
    const float* Bb      = (const float*)d_in[6];
    const float* bias    = (const float*)d_in[7];
    float* out = (float*)d_out;

    char* ws = (char*)d_ws;
    size_t o = 0;
    unsigned short* UT   = (unsigned short*)(ws + o); o += (size_t)RANK * N_IN * 2;
    unsigned short* WT   = (unsigned short*)(ws + o); o += (size_t)RANK * N_CTX * 2;
    unsigned short* Vb   = (unsigned short*)(ws + o); o += (size_t)UNITS * RANK * 2;
    unsigned short* Schi = (unsigned short*)(ws + o); o += (size_t)B_SZ * RANK * 2;
    unsigned short* T    = (unsigned short*)(ws + o); o += (size_t)B_SZ * RANK * 2;
    unsigned short* T0p  = (unsigned short*)(ws + o); o += (size_t)ZSPLIT * B_SZ * RANK * 2;

    prep<<<800, 256, 0, stream>>>(U, W, V, UT, WT, Vb);
    k21<<<512, 512, 0, stream>>>(inputs, UT, T0p, context, WT, S, Bb, Schi);
    e_red<<<(B_SZ * RANK) / (256 * 8), 256, 0, stream>>>(T0p, Schi, T);
    k3_out<<<dim3(32, 8), 512, 0, stream>>>(T, Vb, bias, out);
}